// Round 1
// 153.603 us; speedup vs baseline: 1.0144x; 1.0144x over previous
//
#include <hip/hip_runtime.h>

#define BATCH   2
#define T_LEN   2048
#define C_DIM   1024
#define NH      16
#define NKV     8
#define HD      64

typedef unsigned short u16;
typedef __attribute__((ext_vector_type(8))) short short8;
typedef __attribute__((ext_vector_type(4))) float floatx4;

__device__ __forceinline__ u16 f2bf(float f) {
    union { float f; unsigned u; } v; v.f = f;
    unsigned r = v.u + 0x7FFF + ((v.u >> 16) & 1);   // round-to-nearest-even
    return (u16)(r >> 16);
}

__device__ __forceinline__ void gload_lds16(const u16* g, u16* l) {
    __builtin_amdgcn_global_load_lds(
        (const __attribute__((address_space(1))) void*)g,
        (__attribute__((address_space(3))) void*)l, 16, 0, 0);
}

// ---------------------------------------------------------------------------
// All fp32->bf16 conversions in ONE launch. Segments (1024-elt blocks):
// x:4096 | Wq:1024 | Wk:512 | Wv:512 | Wproj:1024 => grid 7168.
// ---------------------------------------------------------------------------
__global__ __launch_bounds__(256)
void cvt_all(const float* __restrict__ x, const float* __restrict__ Wq,
             const float* __restrict__ Wk, const float* __restrict__ Wv,
             const float* __restrict__ Wp, u16* __restrict__ xb,
             u16* __restrict__ Wqkvb, u16* __restrict__ Wpb) {
    const int blk = blockIdx.x;
    const float* src; u16* dst; long off;
    if (blk < 4096)      { src = x;  dst = xb;              off = (long)blk * 1024; }
    else if (blk < 5120) { src = Wq; dst = Wqkvb;           off = (long)(blk - 4096) * 1024; }
    else if (blk < 5632) { src = Wk; dst = Wqkvb + 1048576; off = (long)(blk - 5120) * 1024; }
    else if (blk < 6144) { src = Wv; dst = Wqkvb + 1572864; off = (long)(blk - 5632) * 1024; }
    else                 { src = Wp; dst = Wpb;             off = (long)(blk - 6144) * 1024; }
    const long i = off + (long)threadIdx.x * 4;
    const float4 f = *(const float4*)&src[i];
    ushort4 o;
    o.x = f2bf(f.x); o.y = f2bf(f.y); o.z = f2bf(f.z); o.w = f2bf(f.w);
    *(ushort4*)&dst[i] = o;
}

// ---------------------------------------------------------------------------
// Fused QKV GEMM, 16x16x32 MFMA, BK=64. T3-min 2-phase pipeline: double-
// buffered LDS, next K-tile's global_load_lds issued BEFORE computing the
// current tile, ONE barrier per K-step (loads fly under the MFMAs instead of
// draining at a serial vmcnt(0)). XOR-chunk staging swizzle (braid-validated):
// lane stages chunk (l&7)^(r&7) of row r=l>>3 — global stays 128B-run
// coalesced, LDS fragment reads 2-way max (free).
// [q|k|v](4096x2048) = xb @ Wqkvb^T. 128x128 tile, 4 waves (2x2 of 64x64).
// XCD swizzle: XCD k owns col-tiles {2k,2k+1} (B-slice resident in XCD L2).
// Epilogue: q/k -> rope+RMS+dot -> esq/esk; v -> direct transposed Vt store.
// LDS 64 KB -> 2 blocks/CU (grid-capped at 2 anyway).
// ---------------------------------------------------------------------------
__global__ __launch_bounds__(256)
void gemm_qkv(const u16* __restrict__ A, const u16* __restrict__ B,
              u16* __restrict__ Vt, float* __restrict__ esq,
              float* __restrict__ esk, const float* __restrict__ cosb,
              const float* __restrict__ sinb, const float* __restrict__ wb) {
    const int K = 1024;
    __shared__ u16 As[2][128 * 64];   // 32 KB
    __shared__ u16 Bs[2][128 * 64];   // 32 KB
    const int tid    = threadIdx.x;
    const int lane   = tid & 63;
    const int wave   = tid >> 6;
    const int row_in = lane & 15;
    const int quad   = lane >> 4;
    const int rw     = (wave & 1) * 64;
    const int cw     = (wave >> 1) * 64;
    const int bi   = blockIdx.x;         // 0..511
    const int xcd  = bi & 7;
    const int bj   = bi >> 3;            // 0..63
    const int row0 = (bj >> 1) * 128;    // 32 row-tiles
    const int col0 = (xcd * 2 + (bj & 1)) * 128;   // 16 col-tiles

    floatx4 acc[4][4] = {};

    const int n    = row_in;
    const int xa   = n & 7;              // fragment-read XOR key

    // staging coordinates (constant per thread across iterations)
    const int sl_r[4]  = { (0*256+tid)>>3, (1*256+tid)>>3, (2*256+tid)>>3, (3*256+tid)>>3 };
    const int sl_kc[4] = { ((0*256+tid)&7)^(sl_r[0]&7), ((1*256+tid)&7)^(sl_r[1]&7),
                           ((2*256+tid)&7)^(sl_r[2]&7), ((3*256+tid)&7)^(sl_r[3]&7) };

    // ---- prologue: stage K-tile 0 into buffer 0 ----
    #pragma unroll
    for (int c = 0; c < 4; ++c) {
        const int l = c * 256 + tid;
        gload_lds16(A + (size_t)(row0 + sl_r[c]) * K + sl_kc[c] * 8, &As[0][(size_t)l * 8]);
        gload_lds16(B + (size_t)(col0 + sl_r[c]) * K + sl_kc[c] * 8, &Bs[0][(size_t)l * 8]);
    }
    __syncthreads();

    int cur = 0;
    for (int k0 = 0; k0 < K; k0 += 64) {
        // ---- issue next tile's loads into the other buffer (flies under MFMAs) ----
        if (k0 + 64 < K) {
            const int kn = k0 + 64;
            #pragma unroll
            for (int c = 0; c < 4; ++c) {
                const int l = c * 256 + tid;
                gload_lds16(A + (size_t)(row0 + sl_r[c]) * K + kn + sl_kc[c] * 8, &As[cur ^ 1][(size_t)l * 8]);
                gload_lds16(B + (size_t)(col0 + sl_r[c]) * K + kn + sl_kc[c] * 8, &Bs[cur ^ 1][(size_t)l * 8]);
            }
        }
        // ---- compute current buffer ----
        #pragma unroll
        for (int kk = 0; kk < 2; ++kk) {
            const int co = ((kk * 4 + quad) ^ xa) * 8;
            short8 af[4], bf_[4];
            #pragma unroll
            for (int i = 0; i < 4; ++i)
                af[i] = *(const short8*)&As[cur][(rw + 16 * i + n) * 64 + co];
            #pragma unroll
            for (int j = 0; j < 4; ++j)
                bf_[j] = *(const short8*)&Bs[cur][(cw + 16 * j + n) * 64 + co];
            #pragma unroll
            for (int i = 0; i < 4; ++i)
                #pragma unroll
                for (int j = 0; j < 4; ++j)
                    acc[i][j] = __builtin_amdgcn_mfma_f32_16x16x32_bf16(af[i], bf_[j], acc[i][j], 0, 0, 0);
        }
        // one barrier per K-step: publishes next buffer (vmcnt drain) AND
        // protects current buffer from being overwritten next iteration.
        __syncthreads();
        cur ^= 1;
    }

    const int cw_g = col0 + cw;
    const int rw_g = row0 + rw;
    const int ch   = cw_g >> 6;          // head 0..31 (q:0-15 k:16-23 v:24-31)

    if (ch < 24) {      // ---- q/k: rope + RMS-norm + dot -> e^-s ----
        const float w0 = wb[n], w1 = wb[16 + n], w2 = wb[32 + n], w3 = wb[48 + n];
        #pragma unroll
        for (int i = 0; i < 4; ++i)
            #pragma unroll
            for (int r = 0; r < 4; ++r) {
                const int grow = rw_g + 16 * i + quad * 4 + r;
                const int t = grow & 2047;
                const int b = grow >> 11;
                const float c0 = cosb[t * 32 + n];
                const float c1 = cosb[t * 32 + 16 + n];
                const float s0 = sinb[t * 32 + n];
                const float s1 = sinb[t * 32 + 16 + n];
                const float x0 = acc[i][0][r], x1 = acc[i][1][r];
                const float x2 = acc[i][2][r], x3 = acc[i][3][r];
                const float r0 = fmaf(x0, c0,  x2 * s0);
                const float r1 = fmaf(x1, c1,  x3 * s1);
                const float r2 = fmaf(x2, c0, -x0 * s0);
                const float r3 = fmaf(x3, c1, -x1 * s1);
                float ss = r0 * r0 + r1 * r1 + r2 * r2 + r3 * r3;
                float dt = r0 * w0 + r1 * w1 + r2 * w2 + r3 * w3;
                #pragma unroll
                for (int m = 1; m < 16; m <<= 1) {
                    ss += __shfl_xor(ss, m, 64);
                    dt += __shfl_xor(dt, m, 64);
                }
                const float val = dt * rsqrtf(ss * (1.0f / 64.0f) + 1e-6f);
                const float e = __expf(-fminf(fmaxf(val, -44.0f), 44.0f));
                if (n == 0) {
                    if (ch < 16) esq[((size_t)b * NH + ch) * T_LEN + t] = e;
                    else         esk[((size_t)b * NKV + ch - 16) * T_LEN + t] = e;
                }
            }
    } else {            // ---- v: direct transposed register->Vt store ----
        const int vcol = cw_g - 1536;            // 0..511; this wave: vcol..vcol+63
        const int b    = rw_g >> 11;             // uniform across block
        const int tb   = (rw_g & 2047) + quad * 4;
        #pragma unroll
        for (int j = 0; j < 4; ++j) {
            const int dg  = vcol + 16 * j + n;   // global v-col 0..511
            const int kvh = dg >> 6;
            const int din = dg & 63;
            u16* dstp = Vt + ((size_t)(b * NKV + kvh) * 64 + din) * T_LEN;
            #pragma unroll
            for (int i = 0; i < 4; ++i) {
                ushort4 o;
                o.x = f2bf(acc[i][j][0]);
                o.y = f2bf(acc[i][j][1]);
                o.z = f2bf(acc[i][j][2]);
                o.w = f2bf(acc[i][j][3]);
                *(ushort4*)&dstp[tb + 16 * i] = o;
            }
        }
    }
}

// ---------------------------------------------------------------------------
// Braid attention, MFMA 16x16x32, 512 threads = 2 s-groups x 4 row-waves.
// P = 1/(1 + esq[t]*esk[s]); no transcendentals (precomputed).
// Triangle pairing (tiles p, 31-p). fp32 LDS cross-group reduction.
// T3-min pipeline: V/esk double-buffered, next 128-chunk staged BEFORE the
// current chunk's compute, ONE barrier per s-step (was 2). Reduction scratch
// is now a dedicated 16 KB buffer (no aliasing hazard with prefetched V).
// XCD swizzle: XCD k owns (b,kvh) groups {2k,2k+1}.
// ---------------------------------------------------------------------------
__global__ __launch_bounds__(512)
void braid_attn(const float* __restrict__ esq, const float* __restrict__ esk,
                const u16* __restrict__ Vt, u16* __restrict__ yb) {
    __shared__ u16 Vd[2][2][4096];  // [buf][64-half][..] XOR-8 swizzled, 32 KB
    __shared__ float eskl[2][128];
    __shared__ float red[4096];     // 16 KB reduction scratch (dedicated)

    const int bi   = blockIdx.x;    // 0..511
    const int g    = (bi & 7) * 2 + ((bi >> 8) & 1);  // (b,kvh) group 0..15
    const int wnd  = (bi >> 3) & 31;                  // 0..31 within group
    const int b    = g >> 3;
    const int kvh  = g & 7;
    const int h    = kvh * 2 + (wnd >> 4);
    const int p    = wnd & 15;      // pair 0..15
    const int bh   = b * 16 + h;
    const int tid  = threadIdx.x;
    const int lane = tid & 63;
    const int wave = tid >> 6;      // 0..7
    const int sg   = wave >> 2;     // s-group
    const int w4   = wave & 3;      // row-wave
    const int n    = lane & 15;
    const int quad = lane >> 4;
    const int row  = w4 * 16 + n;   // t-row within tile

    const float* esq_p = esq + (size_t)bh * T_LEN;
    const float* esk_p = esk + ((size_t)b * NKV + kvh) * T_LEN;
    const u16*   vt_b  = Vt + ((size_t)b * NKV + kvh) * 64 * T_LEN;
    const float  inv   = (float)(1.0 / (45.254833995939045 + 1e-6));

    // staging coordinates (constant per thread)
    const int st_r  = tid >> 3;
    const int st_so = ((tid & 7) ^ (st_r & 7)) << 3;

    for (int ph = 0; ph < 2; ++ph) {
        const int t0 = (ph ? p : (31 - p)) * 64;
        const float a = esq_p[t0 + row];
        const int send = t0 + 64;
        floatx4 acc[4] = {};

        // ---- prologue: stage chunk s0=0 into buffer 0 ----
        gload_lds16(vt_b + (size_t)st_r * T_LEN + st_so, &Vd[0][0][(size_t)tid * 8]);
        if (64 < send)
            gload_lds16(vt_b + (size_t)st_r * T_LEN + 64 + st_so, &Vd[0][1][(size_t)tid * 8]);
        if (tid < 128 && (tid < 64 || 64 < send))
            eskl[0][tid] = esk_p[tid];
        __syncthreads();

        int cur = 0;
        for (int s0 = 0; s0 < send; s0 += 128) {
            // ---- issue next chunk's loads (fly under this chunk's compute) ----
            const int s0n = s0 + 128;
            if (s0n < send) {
                gload_lds16(vt_b + (size_t)st_r * T_LEN + s0n + st_so, &Vd[cur ^ 1][0][(size_t)tid * 8]);
                if (s0n + 64 < send)
                    gload_lds16(vt_b + (size_t)st_r * T_LEN + s0n + 64 + st_so, &Vd[cur ^ 1][1][(size_t)tid * 8]);
                if (tid < 128 && (tid < 64 || s0n + 64 < send))
                    eskl[cur ^ 1][tid] = esk_p[s0n + tid];
            }

            // ---- compute current chunk ----
            const int s0g = s0 + sg * 64;
            if (s0g < send) {
                const bool diag = (s0g == t0);
                #pragma unroll
                for (int kk = 0; kk < 2; ++kk) {
                    const float* eb = &eskl[cur][sg * 64 + kk * 32 + quad * 8];
                    const float4 e0 = *(const float4*)eb;
                    const float4 e1 = *(const float4*)(eb + 4);
                    const float ev[8] = {e0.x, e0.y, e0.z, e0.w, e1.x, e1.y, e1.z, e1.w};
                    union { unsigned u[4]; short8 s8; } af;
                    #pragma unroll
                    for (int jj = 0; jj < 4; ++jj) {
                        float r0 = __builtin_amdgcn_rcpf(fmaf(ev[2 * jj],     a, 1.0f));
                        float r1 = __builtin_amdgcn_rcpf(fmaf(ev[2 * jj + 1], a, 1.0f));
                        if (diag) {
                            const int s_ = kk * 32 + quad * 8 + 2 * jj;
                            if (s_     > row) r0 = 0.0f;
                            if (s_ + 1 > row) r1 = 0.0f;
                        }
                        af.u[jj] = __builtin_amdgcn_perm(__float_as_uint(r1),
                                                         __float_as_uint(r0), 0x07060302u);
                    }
                    #pragma unroll
                    for (int j = 0; j < 4; ++j) {
                        const short8 bfr = *(const short8*)
                            &Vd[cur][sg][(16 * j + n) * 64 + (((kk * 4 + quad) ^ (n & 7)) << 3)];
                        acc[j] = __builtin_amdgcn_mfma_f32_16x16x32_bf16(af.s8, bfr, acc[j], 0, 0, 0);
                    }
                }
            }
            // one barrier per s-step: publishes the prefetched buffer AND
            // protects the buffer we just read from next iteration's stage.
            __syncthreads();
            cur ^= 1;
        }

        // ---- cross-s-group reduction + output (loop ended with a barrier) ----
        if (sg == 1) {
            #pragma unroll
            for (int j = 0; j < 4; ++j)
                #pragma unroll
                for (int r = 0; r < 4; ++r)
                    red[(j * 4 + r) * 256 + w4 * 64 + lane] = acc[j][r];
        }
        __syncthreads();
        if (sg == 0) {
            #pragma unroll
            for (int j = 0; j < 4; ++j)
                #pragma unroll
                for (int r = 0; r < 4; ++r) {
                    const float o = acc[j][r] + red[(j * 4 + r) * 256 + w4 * 64 + lane];
                    const int t = t0 + w4 * 16 + quad * 4 + r;
                    yb[((size_t)b * T_LEN + t) * C_DIM + h * HD + 16 * j + n] = f2bf(o * inv);
                }
        }
    }
}

// ---------------------------------------------------------------------------
// Proj GEMM, 16x16x32 MFMA, 128x64 tile, BK=64 + XOR-chunk swizzle staging.
// T3-min 2-phase pipeline (dbuf + prefetch-before-compute, 1 barrier/iter).
// 4 waves as 2 (rows) x 2 (cols of 32). acc 4x2. XCD swizzle. LDS 48 KB.
// ---------------------------------------------------------------------------
__global__ __launch_bounds__(256)
void gemm_proj(const u16* __restrict__ A, const u16* __restrict__ B,
               float* __restrict__ C, int M, int N, int K) {
    __shared__ u16 As[2][128 * 64];   // 32 KB
    __shared__ u16 Bs[2][64 * 64];    // 16 KB
    const int tid    = threadIdx.x;
    const int lane   = tid & 63;
    const int wave   = tid >> 6;
    const int row_in = lane & 15;
    const int quad   = lane >> 4;
    const int rw     = (wave & 1) * 64;
    const int cw     = (wave >> 1) * 32;
    const int bi   = blockIdx.x;         // 0..511
    const int xcd  = bi & 7;
    const int bj   = bi >> 3;
    const int row0 = (bj >> 1) * 128;
    const int col0 = (xcd * 2 + (bj & 1)) * 64;

    floatx4 acc[4][2] = {};

    const int n  = row_in;
    const int xa = n & 7;

    // ---- prologue: stage K-tile 0 into buffer 0 ----
    #pragma unroll
    for (int c = 0; c < 4; ++c) {
        const int l  = c * 256 + tid;
        const int r  = l >> 3;
        const int kc = (l & 7) ^ (r & 7);
        gload_lds16(A + (size_t)(row0 + r) * K + kc * 8, &As[0][(size_t)l * 8]);
    }
    #pragma unroll
    for (int c = 0; c < 2; ++c) {
        const int l  = c * 256 + tid;
        const int r  = l >> 3;
        const int kc = (l & 7) ^ (r & 7);
        gload_lds16(B + (size_t)(col0 + r) * K + kc * 8, &Bs[0][(size_t)l * 8]);
    }
    __syncthreads();

    int cur = 0;
    for (int k0 = 0; k0 < K; k0 += 64) {
        if (k0 + 64 < K) {
            const int kn = k0 + 64;
            #pragma unroll
            for (int c = 0; c < 4; ++c) {
                const int l  = c * 256 + tid;
                const int r  = l >> 3;
                const int kc = (l & 7) ^ (r & 7);
                gload_lds16(A + (size_t)(row0 + r) * K + kn + kc * 8, &As[cur ^ 1][(size_t)l * 8]);
            }
            #pragma unroll
            for (int c = 0; c < 2; ++c) {
                const int l  = c * 256 + tid;
                const int r  = l >> 3;
                const int kc = (l & 7) ^ (r & 7);
                gload_lds16(B + (size_t)(col0 + r) * K + kn + kc * 8, &Bs[cur ^ 1][(size_t)l * 8]);
            }
        }
        #pragma unroll
        for (int kk = 0; kk < 2; ++kk) {
            const int co = ((kk * 4 + quad) ^ xa) * 8;
            short8 af[4], bf_[2];
            #pragma unroll
            for (int i = 0; i < 4; ++i)
                af[i] = *(const short8*)&As[cur][(rw + 16 * i + n) * 64 + co];
            #pragma unroll
            for (int j = 0; j < 2; ++j)
                bf_[j] = *(const short8*)&Bs[cur][(cw + 16 * j + n) * 64 + co];
            #pragma unroll
            for (int i = 0; i < 4; ++i)
                #pragma unroll
                for (int j = 0; j < 2; ++j)
                    acc[i][j] = __builtin_amdgcn_mfma_f32_16x16x32_bf16(af[i], bf_[j], acc[i][j], 0, 0, 0);
        }
        __syncthreads();
        cur ^= 1;
    }

    #pragma unroll
    for (int i = 0; i < 4; ++i)
        #pragma unroll
        for (int j = 0; j < 2; ++j)
            #pragma unroll
            for (int r = 0; r < 4; ++r)
                C[(size_t)(row0 + rw + 16 * i + quad * 4 + r) * N + col0 + cw + 16 * j + row_in]
                    = acc[i][j][r];
}

// ---------------------------------------------------------------------------
extern "C" void kernel_launch(void* const* d_in, const int* in_sizes, int n_in,
                              void* d_out, int out_size, void* d_ws, size_t ws_size,
                              hipStream_t stream) {
    const float* x     = (const float*)d_in[0];
    const float* cosb  = (const float*)d_in[1];
    const float* sinb  = (const float*)d_in[2];
    const float* Wq    = (const float*)d_in[3];
    const float* Wk    = (const float*)d_in[4];
    const float* Wv    = (const float*)d_in[5];
    const float* Wproj = (const float*)d_in[6];
    const float* wb    = (const float*)d_in[7];
    float* out = (float*)d_out;

    char* w = (char*)d_ws;
    u16* xb     = (u16*)w;  w += (size_t)4096 * 1024 * 2;
    u16* Wqkvb  = (u16*)w;  w += (size_t)2048 * 1024 * 2;   // [Wq; Wk; Wv]
    u16* Wpb    = (u16*)w;  w += (size_t)1024 * 1024 * 2;
    u16* yb     = (u16*)w;  w += (size_t)4096 * 1024 * 2;
    u16* VtB    = (u16*)w;  w += (size_t)BATCH * NKV * 64 * T_LEN * 2;
    float* esq  = (float*)w; w += (size_t)BATCH * NH * T_LEN * 4;
    float* esk  = (float*)w; w += (size_t)BATCH * NKV * T_LEN * 4;

    dim3 blk(256);
    cvt_all<<<7168, blk, 0, stream>>>(x, Wq, Wk, Wv, Wproj, xb, Wqkvb, Wpb);
    gemm_qkv<<<512, blk, 0, stream>>>(xb, Wqkvb, VtB, esq, esk, cosb, sinb, wb);
    braid_attn<<<512, dim3(512), 0, stream>>>(esq, esk, VtB, yb);
    gemm_proj<<<512, blk, 0, stream>>>(yb, Wpb, out, 4096, 1024, 1024);
}

// Round 2
// 147.926 us; speedup vs baseline: 1.0533x; 1.0384x over previous
//
#include <hip/hip_runtime.h>

#define BATCH   2
#define T_LEN   2048
#define C_DIM   1024
#define NH      16
#define NKV     8
#define HD      64

typedef unsigned short u16;
typedef __attribute__((ext_vector_type(8))) short short8;
typedef __attribute__((ext_vector_type(4))) float floatx4;

__device__ __forceinline__ u16 f2bf(float f) {
    union { float f; unsigned u; } v; v.f = f;
    unsigned r = v.u + 0x7FFF + ((v.u >> 16) & 1);   // round-to-nearest-even
    return (u16)(r >> 16);
}

__device__ __forceinline__ void gload_lds16(const u16* g, u16* l) {
    __builtin_amdgcn_global_load_lds(
        (const __attribute__((address_space(1))) void*)g,
        (__attribute__((address_space(3))) void*)l, 16, 0, 0);
}

#define SBAR   __builtin_amdgcn_s_barrier()
#define SCHED0 __builtin_amdgcn_sched_barrier(0)
#define WAIT_LGKM0 asm volatile("s_waitcnt lgkmcnt(0)" ::: "memory")

// ---------------------------------------------------------------------------
// All fp32->bf16 conversions in ONE launch. Segments (1024-elt blocks):
// x:4096 | Wq:1024 | Wk:512 | Wv:512 | Wproj:1024 => grid 7168.
// ---------------------------------------------------------------------------
__global__ __launch_bounds__(256)
void cvt_all(const float* __restrict__ x, const float* __restrict__ Wq,
             const float* __restrict__ Wk, const float* __restrict__ Wv,
             const float* __restrict__ Wp, u16* __restrict__ xb,
             u16* __restrict__ Wqkvb, u16* __restrict__ Wpb) {
    const int blk = blockIdx.x;
    const float* src; u16* dst; long off;
    if (blk < 4096)      { src = x;  dst = xb;              off = (long)blk * 1024; }
    else if (blk < 5120) { src = Wq; dst = Wqkvb;           off = (long)(blk - 4096) * 1024; }
    else if (blk < 5632) { src = Wk; dst = Wqkvb + 1048576; off = (long)(blk - 5120) * 1024; }
    else if (blk < 6144) { src = Wv; dst = Wqkvb + 1572864; off = (long)(blk - 5632) * 1024; }
    else                 { src = Wp; dst = Wpb;             off = (long)(blk - 6144) * 1024; }
    const long i = off + (long)threadIdx.x * 4;
    const float4 f = *(const float4*)&src[i];
    ushort4 o;
    o.x = f2bf(f.x); o.y = f2bf(f.y); o.z = f2bf(f.z); o.w = f2bf(f.w);
    *(ushort4*)&dst[i] = o;
}

// ---------------------------------------------------------------------------
// Fused QKV GEMM, 16x16x32 MFMA, BK=64. Depth-2 counted-vmcnt pipeline (T4):
// raw s_barrier (NO implicit vmcnt(0) drain), loads for tile k+2 issued while
// tile k computes; vmcnt(8) lets the newest 8 loads stay in flight across the
// barrier. Per iter: ds_read all frags -> lgkm0 -> barrier (reads published)
// -> issue k+2 into just-read buffer -> MFMA -> vmcnt(8) (k+1 ready) ->
// barrier. XOR-chunk staging swizzle (braid-validated) unchanged.
// [q|k|v](4096x2048) = xb @ Wqkvb^T. 128x128 tile, 4 waves (2x2 of 64x64).
// XCD swizzle: XCD k owns col-tiles {2k,2k+1}.
// Epilogue: q/k -> rope+RMS+dot -> esq/esk; v -> direct transposed Vt store.
// ---------------------------------------------------------------------------
__global__ __launch_bounds__(256)
void gemm_qkv(const u16* __restrict__ A, const u16* __restrict__ B,
              u16* __restrict__ Vt, float* __restrict__ esq,
              float* __restrict__ esk, const float* __restrict__ cosb,
              const float* __restrict__ sinb, const float* __restrict__ wb) {
    const int K  = 1024;
    const int NK = 16;                 // K / 64
    __shared__ u16 As[2][128 * 64];    // 32 KB
    __shared__ u16 Bs[2][128 * 64];    // 32 KB
    const int tid    = threadIdx.x;
    const int lane   = tid & 63;
    const int wave   = tid >> 6;
    const int row_in = lane & 15;
    const int quad   = lane >> 4;
    const int rw     = (wave & 1) * 64;
    const int cw     = (wave >> 1) * 64;
    const int bi   = blockIdx.x;         // 0..511
    const int xcd  = bi & 7;
    const int bj   = bi >> 3;            // 0..63
    const int row0 = (bj >> 1) * 128;    // 32 row-tiles
    const int col0 = (xcd * 2 + (bj & 1)) * 128;   // 16 col-tiles

    floatx4 acc[4][4] = {};

    const int n    = row_in;
    const int xa   = n & 7;              // fragment-read XOR key

    // staging coordinates (constant per thread across iterations)
    const int sl_r[4]  = { (0*256+tid)>>3, (1*256+tid)>>3, (2*256+tid)>>3, (3*256+tid)>>3 };
    const int sl_kc[4] = { ((0*256+tid)&7)^(sl_r[0]&7), ((1*256+tid)&7)^(sl_r[1]&7),
                           ((2*256+tid)&7)^(sl_r[2]&7), ((3*256+tid)&7)^(sl_r[3]&7) };

    // ---- prologue: stage tiles 0 and 1 (8 vm-ops each per wave) ----
    #pragma unroll
    for (int c = 0; c < 4; ++c) {
        const int l = c * 256 + tid;
        gload_lds16(A + (size_t)(row0 + sl_r[c]) * K + 0  + sl_kc[c] * 8, &As[0][(size_t)l * 8]);
        gload_lds16(B + (size_t)(col0 + sl_r[c]) * K + 0  + sl_kc[c] * 8, &Bs[0][(size_t)l * 8]);
    }
    #pragma unroll
    for (int c = 0; c < 4; ++c) {
        const int l = c * 256 + tid;
        gload_lds16(A + (size_t)(row0 + sl_r[c]) * K + 64 + sl_kc[c] * 8, &As[1][(size_t)l * 8]);
        gload_lds16(B + (size_t)(col0 + sl_r[c]) * K + 64 + sl_kc[c] * 8, &Bs[1][(size_t)l * 8]);
    }
    asm volatile("s_waitcnt vmcnt(8)" ::: "memory");   // tile-0 loads complete
    SBAR;
    SCHED0;

    int cur = 0;
    for (int kt = 0; kt < NK; ++kt) {
        // ---- 1. read ALL fragments of buf[cur] into registers ----
        short8 af[2][4], bf_[2][4];
        #pragma unroll
        for (int kk = 0; kk < 2; ++kk) {
            const int co = ((kk * 4 + quad) ^ xa) * 8;
            #pragma unroll
            for (int i = 0; i < 4; ++i)
                af[kk][i] = *(const short8*)&As[cur][(rw + 16 * i + n) * 64 + co];
            #pragma unroll
            for (int j = 0; j < 4; ++j)
                bf_[kk][j] = *(const short8*)&Bs[cur][(cw + 16 * j + n) * 64 + co];
        }
        WAIT_LGKM0;          // reads COMPLETE (not just issued)
        SCHED0;
        SBAR;                // all waves done reading buf[cur] -> safe to overwrite
        SCHED0;

        // ---- 2. issue tile kt+2 into buf[cur] (flies across the next barrier) ----
        if (kt + 2 < NK) {
            const int kn = (kt + 2) * 64;
            #pragma unroll
            for (int c = 0; c < 4; ++c) {
                const int l = c * 256 + tid;
                gload_lds16(A + (size_t)(row0 + sl_r[c]) * K + kn + sl_kc[c] * 8, &As[cur][(size_t)l * 8]);
                gload_lds16(B + (size_t)(col0 + sl_r[c]) * K + kn + sl_kc[c] * 8, &Bs[cur][(size_t)l * 8]);
            }
        }

        // ---- 3. MFMA (register-only; overlaps the in-flight loads) ----
        #pragma unroll
        for (int kk = 0; kk < 2; ++kk)
            #pragma unroll
            for (int i = 0; i < 4; ++i)
                #pragma unroll
                for (int j = 0; j < 4; ++j)
                    acc[i][j] = __builtin_amdgcn_mfma_f32_16x16x32_bf16(af[kk][i], bf_[kk][j], acc[i][j], 0, 0, 0);

        // ---- 4. counted wait: tile kt+1's 8 loads done; kt+2's 8 stay in flight ----
        if (kt < NK - 2) { asm volatile("s_waitcnt vmcnt(8)" ::: "memory"); }
        else             { asm volatile("s_waitcnt vmcnt(0)" ::: "memory"); }
        SBAR;
        SCHED0;
        cur ^= 1;
    }

    const int cw_g = col0 + cw;
    const int rw_g = row0 + rw;
    const int ch   = cw_g >> 6;          // head 0..31 (q:0-15 k:16-23 v:24-31)

    if (ch < 24) {      // ---- q/k: rope + RMS-norm + dot -> e^-s ----
        const float w0 = wb[n], w1 = wb[16 + n], w2 = wb[32 + n], w3 = wb[48 + n];
        #pragma unroll
        for (int i = 0; i < 4; ++i)
            #pragma unroll
            for (int r = 0; r < 4; ++r) {
                const int grow = rw_g + 16 * i + quad * 4 + r;
                const int t = grow & 2047;
                const int b = grow >> 11;
                const float c0 = cosb[t * 32 + n];
                const float c1 = cosb[t * 32 + 16 + n];
                const float s0 = sinb[t * 32 + n];
                const float s1 = sinb[t * 32 + 16 + n];
                const float x0 = acc[i][0][r], x1 = acc[i][1][r];
                const float x2 = acc[i][2][r], x3 = acc[i][3][r];
                const float r0 = fmaf(x0, c0,  x2 * s0);
                const float r1 = fmaf(x1, c1,  x3 * s1);
                const float r2 = fmaf(x2, c0, -x0 * s0);
                const float r3 = fmaf(x3, c1, -x1 * s1);
                float ss = r0 * r0 + r1 * r1 + r2 * r2 + r3 * r3;
                float dt = r0 * w0 + r1 * w1 + r2 * w2 + r3 * w3;
                #pragma unroll
                for (int m = 1; m < 16; m <<= 1) {
                    ss += __shfl_xor(ss, m, 64);
                    dt += __shfl_xor(dt, m, 64);
                }
                const float val = dt * rsqrtf(ss * (1.0f / 64.0f) + 1e-6f);
                const float e = __expf(-fminf(fmaxf(val, -44.0f), 44.0f));
                if (n == 0) {
                    if (ch < 16) esq[((size_t)b * NH + ch) * T_LEN + t] = e;
                    else         esk[((size_t)b * NKV + ch - 16) * T_LEN + t] = e;
                }
            }
    } else {            // ---- v: direct transposed register->Vt store ----
        const int vcol = cw_g - 1536;            // 0..511; this wave: vcol..vcol+63
        const int b    = rw_g >> 11;             // uniform across block
        const int tb   = (rw_g & 2047) + quad * 4;
        #pragma unroll
        for (int j = 0; j < 4; ++j) {
            const int dg  = vcol + 16 * j + n;   // global v-col 0..511
            const int kvh = dg >> 6;
            const int din = dg & 63;
            u16* dstp = Vt + ((size_t)(b * NKV + kvh) * 64 + din) * T_LEN;
            #pragma unroll
            for (int i = 0; i < 4; ++i) {
                ushort4 o;
                o.x = f2bf(acc[i][j][0]);
                o.y = f2bf(acc[i][j][1]);
                o.z = f2bf(acc[i][j][2]);
                o.w = f2bf(acc[i][j][3]);
                *(ushort4*)&dstp[tb + 16 * i] = o;
            }
        }
    }
}

// ---------------------------------------------------------------------------
// Braid attention, MFMA 16x16x32, 512 threads = 2 s-groups x 4 row-waves.
// P = 1/(1 + esq[t]*esk[s]); no transcendentals (precomputed).
// Triangle pairing (tiles p, 31-p). fp32 LDS cross-group reduction.
// T3-min pipeline: V/esk double-buffered, next 128-chunk staged BEFORE the
// current chunk's compute, ONE barrier per s-step.
// XCD swizzle: XCD k owns (b,kvh) groups {2k,2k+1}.
// ---------------------------------------------------------------------------
__global__ __launch_bounds__(512)
void braid_attn(const float* __restrict__ esq, const float* __restrict__ esk,
                const u16* __restrict__ Vt, u16* __restrict__ yb) {
    __shared__ u16 Vd[2][2][4096];  // [buf][64-half][..] XOR-8 swizzled, 32 KB
    __shared__ float eskl[2][128];
    __shared__ float red[4096];     // 16 KB reduction scratch (dedicated)

    const int bi   = blockIdx.x;    // 0..511
    const int g    = (bi & 7) * 2 + ((bi >> 8) & 1);  // (b,kvh) group 0..15
    const int wnd  = (bi >> 3) & 31;                  // 0..31 within group
    const int b    = g >> 3;
    const int kvh  = g & 7;
    const int h    = kvh * 2 + (wnd >> 4);
    const int p    = wnd & 15;      // pair 0..15
    const int bh   = b * 16 + h;
    const int tid  = threadIdx.x;
    const int lane = tid & 63;
    const int wave = tid >> 6;      // 0..7
    const int sg   = wave >> 2;     // s-group
    const int w4   = wave & 3;      // row-wave
    const int n    = lane & 15;
    const int quad = lane >> 4;
    const int row  = w4 * 16 + n;   // t-row within tile

    const float* esq_p = esq + (size_t)bh * T_LEN;
    const float* esk_p = esk + ((size_t)b * NKV + kvh) * T_LEN;
    const u16*   vt_b  = Vt + ((size_t)b * NKV + kvh) * 64 * T_LEN;
    const float  inv   = (float)(1.0 / (45.254833995939045 + 1e-6));

    // staging coordinates (constant per thread)
    const int st_r  = tid >> 3;
    const int st_so = ((tid & 7) ^ (st_r & 7)) << 3;

    for (int ph = 0; ph < 2; ++ph) {
        const int t0 = (ph ? p : (31 - p)) * 64;
        const float a = esq_p[t0 + row];
        const int send = t0 + 64;
        floatx4 acc[4] = {};

        // ---- prologue: stage chunk s0=0 into buffer 0 ----
        gload_lds16(vt_b + (size_t)st_r * T_LEN + st_so, &Vd[0][0][(size_t)tid * 8]);
        if (64 < send)
            gload_lds16(vt_b + (size_t)st_r * T_LEN + 64 + st_so, &Vd[0][1][(size_t)tid * 8]);
        if (tid < 128 && (tid < 64 || 64 < send))
            eskl[0][tid] = esk_p[tid];
        __syncthreads();

        int cur = 0;
        for (int s0 = 0; s0 < send; s0 += 128) {
            // ---- issue next chunk's loads (fly under this chunk's compute) ----
            const int s0n = s0 + 128;
            if (s0n < send) {
                gload_lds16(vt_b + (size_t)st_r * T_LEN + s0n + st_so, &Vd[cur ^ 1][0][(size_t)tid * 8]);
                if (s0n + 64 < send)
                    gload_lds16(vt_b + (size_t)st_r * T_LEN + s0n + 64 + st_so, &Vd[cur ^ 1][1][(size_t)tid * 8]);
                if (tid < 128 && (tid < 64 || s0n + 64 < send))
                    eskl[cur ^ 1][tid] = esk_p[s0n + tid];
            }

            // ---- compute current chunk ----
            const int s0g = s0 + sg * 64;
            if (s0g < send) {
                const bool diag = (s0g == t0);
                #pragma unroll
                for (int kk = 0; kk < 2; ++kk) {
                    const float* eb = &eskl[cur][sg * 64 + kk * 32 + quad * 8];
                    const float4 e0 = *(const float4*)eb;
                    const float4 e1 = *(const float4*)(eb + 4);
                    const float ev[8] = {e0.x, e0.y, e0.z, e0.w, e1.x, e1.y, e1.z, e1.w};
                    union { unsigned u[4]; short8 s8; } af;
                    #pragma unroll
                    for (int jj = 0; jj < 4; ++jj) {
                        float r0 = __builtin_amdgcn_rcpf(fmaf(ev[2 * jj],     a, 1.0f));
                        float r1 = __builtin_amdgcn_rcpf(fmaf(ev[2 * jj + 1], a, 1.0f));
                        if (diag) {
                            const int s_ = kk * 32 + quad * 8 + 2 * jj;
                            if (s_     > row) r0 = 0.0f;
                            if (s_ + 1 > row) r1 = 0.0f;
                        }
                        af.u[jj] = __builtin_amdgcn_perm(__float_as_uint(r1),
                                                         __float_as_uint(r0), 0x07060302u);
                    }
                    #pragma unroll
                    for (int j = 0; j < 4; ++j) {
                        const short8 bfr = *(const short8*)
                            &Vd[cur][sg][(16 * j + n) * 64 + (((kk * 4 + quad) ^ (n & 7)) << 3)];
                        acc[j] = __builtin_amdgcn_mfma_f32_16x16x32_bf16(af.s8, bfr, acc[j], 0, 0, 0);
                    }
                }
            }
            // one barrier per s-step: publishes the prefetched buffer AND
            // protects the buffer we just read from next iteration's stage.
            __syncthreads();
            cur ^= 1;
        }

        // ---- cross-s-group reduction + output (loop ended with a barrier) ----
        if (sg == 1) {
            #pragma unroll
            for (int j = 0; j < 4; ++j)
                #pragma unroll
                for (int r = 0; r < 4; ++r)
                    red[(j * 4 + r) * 256 + w4 * 64 + lane] = acc[j][r];
        }
        __syncthreads();
        if (sg == 0) {
            #pragma unroll
            for (int j = 0; j < 4; ++j)
                #pragma unroll
                for (int r = 0; r < 4; ++r) {
                    const float o = acc[j][r] + red[(j * 4 + r) * 256 + w4 * 64 + lane];
                    const int t = t0 + w4 * 16 + quad * 4 + r;
                    yb[((size_t)b * T_LEN + t) * C_DIM + h * HD + 16 * j + n] = f2bf(o * inv);
                }
        }
    }
}

// ---------------------------------------------------------------------------
// Proj GEMM, 16x16x32 MFMA, 128x64 tile, BK=64 + XOR-chunk swizzle staging.
// Depth-2 counted-vmcnt pipeline (same schedule as gemm_qkv; 6 vm-ops/iter).
// 4 waves as 2 (rows) x 2 (cols of 32). acc 4x2. XCD swizzle.
// ---------------------------------------------------------------------------
__global__ __launch_bounds__(256)
void gemm_proj(const u16* __restrict__ A, const u16* __restrict__ B,
               float* __restrict__ C, int M, int N, int K) {
    const int NK = 16;                // K / 64 (K==1024)
    __shared__ u16 As[2][128 * 64];   // 32 KB
    __shared__ u16 Bs[2][64 * 64];    // 16 KB
    const int tid    = threadIdx.x;
    const int lane   = tid & 63;
    const int wave   = tid >> 6;
    const int row_in = lane & 15;
    const int quad   = lane >> 4;
    const int rw     = (wave & 1) * 64;
    const int cw     = (wave >> 1) * 32;
    const int bi   = blockIdx.x;         // 0..511
    const int xcd  = bi & 7;
    const int bj   = bi >> 3;
    const int row0 = (bj >> 1) * 128;
    const int col0 = (xcd * 2 + (bj & 1)) * 64;

    floatx4 acc[4][2] = {};

    const int n  = row_in;
    const int xa = n & 7;

    // staging coordinates
    const int sa_r[4]  = { (0*256+tid)>>3, (1*256+tid)>>3, (2*256+tid)>>3, (3*256+tid)>>3 };
    const int sa_kc[4] = { ((0*256+tid)&7)^(sa_r[0]&7), ((1*256+tid)&7)^(sa_r[1]&7),
                           ((2*256+tid)&7)^(sa_r[2]&7), ((3*256+tid)&7)^(sa_r[3]&7) };
    const int sb_r[2]  = { (0*256+tid)>>3, (1*256+tid)>>3 };
    const int sb_kc[2] = { ((0*256+tid)&7)^(sb_r[0]&7), ((1*256+tid)&7)^(sb_r[1]&7) };

    // ---- prologue: stage tiles 0 and 1 (6 vm-ops each per wave) ----
    #pragma unroll
    for (int c = 0; c < 4; ++c)
        gload_lds16(A + (size_t)(row0 + sa_r[c]) * K + 0 + sa_kc[c] * 8, &As[0][(size_t)(c*256+tid) * 8]);
    #pragma unroll
    for (int c = 0; c < 2; ++c)
        gload_lds16(B + (size_t)(col0 + sb_r[c]) * K + 0 + sb_kc[c] * 8, &Bs[0][(size_t)(c*256+tid) * 8]);
    #pragma unroll
    for (int c = 0; c < 4; ++c)
        gload_lds16(A + (size_t)(row0 + sa_r[c]) * K + 64 + sa_kc[c] * 8, &As[1][(size_t)(c*256+tid) * 8]);
    #pragma unroll
    for (int c = 0; c < 2; ++c)
        gload_lds16(B + (size_t)(col0 + sb_r[c]) * K + 64 + sb_kc[c] * 8, &Bs[1][(size_t)(c*256+tid) * 8]);
    asm volatile("s_waitcnt vmcnt(6)" ::: "memory");   // tile-0 loads complete
    SBAR;
    SCHED0;

    int cur = 0;
    for (int kt = 0; kt < NK; ++kt) {
        // ---- 1. read ALL fragments of buf[cur] ----
        short8 af[2][4], bf_[2][2];
        #pragma unroll
        for (int kk = 0; kk < 2; ++kk) {
            const int co = ((kk * 4 + quad) ^ xa) * 8;
            #pragma unroll
            for (int i = 0; i < 4; ++i)
                af[kk][i] = *(const short8*)&As[cur][(rw + 16 * i + n) * 64 + co];
            #pragma unroll
            for (int j = 0; j < 2; ++j)
                bf_[kk][j] = *(const short8*)&Bs[cur][(cw + 16 * j + n) * 64 + co];
        }
        WAIT_LGKM0;
        SCHED0;
        SBAR;
        SCHED0;

        // ---- 2. issue tile kt+2 into buf[cur] ----
        if (kt + 2 < NK) {
            const int kn = (kt + 2) * 64;
            #pragma unroll
            for (int c = 0; c < 4; ++c)
                gload_lds16(A + (size_t)(row0 + sa_r[c]) * K + kn + sa_kc[c] * 8, &As[cur][(size_t)(c*256+tid) * 8]);
            #pragma unroll
            for (int c = 0; c < 2; ++c)
                gload_lds16(B + (size_t)(col0 + sb_r[c]) * K + kn + sb_kc[c] * 8, &Bs[cur][(size_t)(c*256+tid) * 8]);
        }

        // ---- 3. MFMA ----
        #pragma unroll
        for (int kk = 0; kk < 2; ++kk)
            #pragma unroll
            for (int i = 0; i < 4; ++i)
                #pragma unroll
                for (int j = 0; j < 2; ++j)
                    acc[i][j] = __builtin_amdgcn_mfma_f32_16x16x32_bf16(af[kk][i], bf_[kk][j], acc[i][j], 0, 0, 0);

        // ---- 4. counted wait ----
        if (kt < NK - 2) { asm volatile("s_waitcnt vmcnt(6)" ::: "memory"); }
        else             { asm volatile("s_waitcnt vmcnt(0)" ::: "memory"); }
        SBAR;
        SCHED0;
        cur ^= 1;
    }

    #pragma unroll
    for (int i = 0; i < 4; ++i)
        #pragma unroll
        for (int j = 0; j < 2; ++j)
            #pragma unroll
            for (int r = 0; r < 4; ++r)
                C[(size_t)(row0 + rw + 16 * i + quad * 4 + r) * N + col0 + cw + 16 * j + row_in]
                    = acc[i][j][r];
}

// ---------------------------------------------------------------------------
extern "C" void kernel_launch(void* const* d_in, const int* in_sizes, int n_in,
                              void* d_out, int out_size, void* d_ws, size_t ws_size,
                              hipStream_t stream) {
    const float* x     = (const float*)d_in[0];
    const float* cosb  = (const float*)d_in[1];
    const float* sinb  = (const float*)d_in[2];
    const float* Wq    = (const float*)d_in[3];
    const float* Wk    = (const float*)d_in[4];
    const float* Wv    = (const float*)d_in[5];
    const float* Wproj = (const float*)d_in[6];
    const float* wb    = (const float*)d_in[7];
    float* out = (float*)d_out;

    char* w = (char*)d_ws;
    u16* xb     = (u16*)w;  w += (size_t)4096 * 1024 * 2;
    u16* Wqkvb  = (u16*)w;  w += (size_t)2048 * 1024 * 2;   // [Wq; Wk; Wv]
    u16* Wpb    = (u16*)w;  w += (size_t)1024 * 1024 * 2;
    u16* yb     = (u16*)w;  w += (size_t)4096 * 1024 * 2;
    u16* VtB    = (u16*)w;  w += (size_t)BATCH * NKV * 64 * T_LEN * 2;
    float* esq  = (float*)w; w += (size_t)BATCH * NH * T_LEN * 4;
    float* esk  = (float*)w; w += (size_t)BATCH * NKV * T_LEN * 4;

    dim3 blk(256);
    cvt_all<<<7168, blk, 0, stream>>>(x, Wq, Wk, Wv, Wproj, xb, Wqkvb, Wpb);
    gemm_qkv<<<512, blk, 0, stream>>>(xb, Wqkvb, VtB, esq, esk, cosb, sinb, wb);
    braid_attn<<<512, dim3(512), 0, stream>>>(esq, esk, VtB, yb);
    gemm_proj<<<512, blk, 0, stream>>>(yb, Wpb, out, 4096, 1024, 1024);
}